// Round 5
// baseline (103.154 us; speedup 1.0000x reference)
//
#include <hip/hip_runtime.h>

#define VDIM   32
#define NPAIR  496              // 32*31/2
#define NBASIS 14               // DEG + ORDER - 1
#define NPARAM (NBASIS * NPAIR) // 6944
#define NINT   11               // distinct tap windows: i-3 in 0..10
#define ROWS   8                // rows per block
#define LROW   544              // padded lam row: seg(31)+31 = 543

typedef float f32x4 __attribute__((ext_vector_type(4)));

// Start of row v's segment in the quad-aligned lam layout (multiple of 4):
__device__ __forceinline__ int seg_of(int v) {
    int m = v - 1;
    if (m <= 0) return 0;
    int q = m >> 2, r = m & 3;
    return 4 * (2 * q * (q + 1) + r * (q + 1));
}

// ---- Prep: blocks 0..10 build ptv[i][p] = params[i..i+3, p]; block 11 = penalties ----
__global__ __launch_bounds__(256) void Decorrelation_prep(
    const float* __restrict__ params,   // [14,496] k-major
    f32x4* __restrict__ ptv,            // [11][496] float4, i-major
    float* __restrict__ pens)           // [3]
{
    const int tid = threadIdx.x;
    const int b   = blockIdx.x;
    if (b < NINT) {
        const int i = b;
        for (int p = tid; p < NPAIR; p += 256) {
            f32x4 w = { params[(i    ) * NPAIR + p],
                        params[(i + 1) * NPAIR + p],
                        params[(i + 2) * NPAIR + p],
                        params[(i + 3) * NPAIR + p] };
            ptv[i * NPAIR + p] = w;
        }
    } else {
        float s2 = 0.f, s1 = 0.f, sp = 0.f;
        for (int idx = tid; idx < NPARAM; idx += 256) {
            const float a = params[idx];
            sp += a * a;
            if (idx < NPARAM - NPAIR) {
                const float bb = params[idx + NPAIR];
                const float d1 = bb - a;
                s1 += d1 * d1;
                if (idx < NPARAM - 2 * NPAIR) {
                    const float cc = params[idx + 2 * NPAIR];
                    const float d2 = cc - 2.f * bb + a;
                    s2 += d2 * d2;
                }
            }
        }
        #pragma unroll
        for (int off = 32; off > 0; off >>= 1) {
            s2 += __shfl_down(s2, off);
            s1 += __shfl_down(s1, off);
            sp += __shfl_down(sp, off);
        }
        __shared__ float ws[3][4];
        const int lane = tid & 63, wid = tid >> 6;
        if (lane == 0) { ws[0][wid] = s2; ws[1][wid] = s1; ws[2][wid] = sp; }
        __syncthreads();
        if (tid == 0) {
            pens[0] = ws[0][0] + ws[0][1] + ws[0][2] + ws[0][3];
            pens[1] = ws[1][0] + ws[1][1] + ws[1][2] + ws[1][3];
            pens[2] = ws[2][0] + ws[2][1] + ws[2][2] + ws[2][3];
        }
    }
}

// ---- Main: 2048 blocks x 256 threads; LDS = lam only (17.4 KB) ----
__global__ __launch_bounds__(256, 4) void Decorrelation_35270271435435_kernel(
    const float* __restrict__ input,    // [N,32]
    const f32x4* __restrict__ ptv,      // [11][496] tap windows, i-major
    float* __restrict__ out,            // [N,32]
    float* __restrict__ lm,             // [N,32,32]
    int N)
{
    __shared__ float lam[ROWS][LROW];   // quad-aligned segmented lam

    const int tid = threadIdx.x;
    const int n0  = blockIdx.x * ROWS;

    // ---- Per-thread pair decode (p1 = tid, p2 = tid+256) ----
    const int p1 = tid;
    int v1 = (int)((1.0f + sqrtf(8.0f * (float)p1 + 1.0f)) * 0.5f);
    while (v1 * (v1 - 1) / 2 > p1) --v1;
    while ((v1 + 1) * v1 / 2 <= p1) ++v1;
    const int c1 = p1 - v1 * (v1 - 1) / 2;
    const int o1 = seg_of(v1) + c1;

    const int  p2   = tid + 256;
    const bool has2 = (p2 < NPAIR);
    int c2 = 0, o2 = 0;
    if (has2) {
        int v2 = (int)((1.0f + sqrtf(8.0f * (float)p2 + 1.0f)) * 0.5f);
        while (v2 * (v2 - 1) / 2 > p2) --v2;
        while ((v2 + 1) * v2 / 2 <= p2) ++v2;
        c2 = p2 - v2 * (v2 - 1) / 2;
        o2 = seg_of(v2) + c2;
    }

    const float dist  = 30.0f / 11.0f;
    const float invd  = 11.0f / 30.0f;
    const float t0    = -15.0f - 3.0f * dist;
    const float sixth = 1.0f / 6.0f;

    // ---- Phase A: weights in-register, params via L1-hot ptv gather ----
    #pragma unroll 4
    for (int r = 0; r < ROWS; ++r) {
        const int base = (n0 + r) * VDIM;
        {
            const float xi = input[base + c1];          // 1-2 lines/wave (L1)
            float x = fminf(fmaxf(xi, -15.0f), 15.0f - 1e-6f);
            float u = (x - t0) * invd;
            int   i = (int)floorf(u);
            i = min(13, max(3, i));
            const float uu  = u - (float)i;
            const float om  = 1.0f - uu;
            const float uu2 = uu * uu, uu3 = uu2 * uu;
            const float w0 = om * om * om * sixth;
            const float w1 = (3.0f * uu3 - 6.0f * uu2 + 4.0f) * sixth;
            const float w2 = (-3.0f * uu3 + 3.0f * uu2 + 3.0f * uu + 1.0f) * sixth;
            const float w3 = uu3 * sixth;
            const f32x4 q  = ptv[(i - 3) * NPAIR + p1];
            lam[r][o1] = w0 * q.x + w1 * q.y + w2 * q.z + w3 * q.w;
        }
        if (has2) {
            const float xi = input[base + c2];
            float x = fminf(fmaxf(xi, -15.0f), 15.0f - 1e-6f);
            float u = (x - t0) * invd;
            int   i = (int)floorf(u);
            i = min(13, max(3, i));
            const float uu  = u - (float)i;
            const float om  = 1.0f - uu;
            const float uu2 = uu * uu, uu3 = uu2 * uu;
            const float w0 = om * om * om * sixth;
            const float w1 = (3.0f * uu3 - 6.0f * uu2 + 4.0f) * sixth;
            const float w2 = (-3.0f * uu3 + 3.0f * uu2 + 3.0f * uu + 1.0f) * sixth;
            const float w3 = uu3 * sixth;
            const f32x4 q  = ptv[(i - 3) * NPAIR + p2];
            lam[r][o2] = w0 * q.x + w1 * q.y + w2 * q.z + w3 * q.w;
        }
    }
    __syncthreads();

    // ---- Phase B: emit lm (coalesced float4 NT stores) + out ----
    const int v    = tid >> 3;
    const int c0   = (tid & 7) << 2;
    const int segv = seg_of(v);
    float* lmp = lm + (size_t)n0 * (VDIM * VDIM) + tid * 4;

    #pragma unroll
    for (int r = 0; r < ROWS; ++r, lmp += VDIM * VDIM) {
        const int n = n0 + r;
        const f32x4 lq = *(const f32x4*)&lam[r][segv + c0];
        const f32x4 xq = *(const f32x4*)(input + n * VDIM + c0);  // L1 broadcast
        float vals[4];
        float partial = 0.0f;
        #pragma unroll
        for (int j = 0; j < 4; ++j) {
            const int c = c0 + j;
            const float lv = (j == 0) ? lq.x : (j == 1) ? lq.y : (j == 2) ? lq.z : lq.w;
            const float xv = (j == 0) ? xq.x : (j == 1) ? xq.y : (j == 2) ? xq.z : xq.w;
            const float val = (c < v) ? lv : ((c == v) ? 1.0f : 0.0f);
            vals[j] = val;
            partial += val * xv;
        }
        f32x4 f4 = { vals[0], vals[1], vals[2], vals[3] };
        __builtin_nontemporal_store(f4, (f32x4*)lmp);

        partial += __shfl_down(partial, 4, 8);
        partial += __shfl_down(partial, 2, 8);
        partial += __shfl_down(partial, 1, 8);
        if ((tid & 7) == 0) out[n * VDIM + v] = partial;
    }
}

extern "C" void kernel_launch(void* const* d_in, const int* in_sizes, int n_in,
                              void* d_out, int out_size, void* d_ws, size_t ws_size,
                              hipStream_t stream) {
    const float* input  = (const float*)d_in[0];   // [N,32]
    // d_in[1] = log_d : unused by the reference
    const float* params = (const float*)d_in[2];   // [14,496]
    const int N = in_sizes[0] / VDIM;              // 16384

    float* out  = (float*)d_out;                   // [N,32]
    float* lm   = out + (size_t)N * VDIM;          // [N,32,32]
    float* pens = lm + (size_t)N * VDIM * VDIM;    // [3]

    f32x4* ptv = (f32x4*)d_ws;                     // [11][496] float4 = 87 KB

    Decorrelation_prep<<<NINT + 1, 256, 0, stream>>>(params, ptv, pens);

    const int nb = (N + ROWS - 1) / ROWS;          // 2048
    Decorrelation_35270271435435_kernel<<<nb, 256, 0, stream>>>(
        input, ptv, out, lm, N);
}

// Round 6
// 102.395 us; speedup vs baseline: 1.0074x; 1.0074x over previous
//
#include <hip/hip_runtime.h>

#define VDIM   32
#define NPAIR  496              // 32*31/2
#define NBASIS 14               // DEG + ORDER - 1
#define NPARAM (NBASIS * NPAIR) // 6944
#define NINT   11               // distinct tap windows: i-3 in 0..10
#define ROWS   8                // rows per block (2 per wave)
#define LROW   544              // padded lam row: seg(31)+31 = 543

typedef float f32x4 __attribute__((ext_vector_type(4)));

// Start of row v's segment in the quad-aligned lam layout (multiple of 4):
__device__ __forceinline__ int seg_of(int v) {
    int m = v - 1;
    if (m <= 0) return 0;
    int q = m >> 2, r = m & 3;
    return 4 * (2 * q * (q + 1) + r * (q + 1));
}

// ---- Prep: blocks 0..10 build ptv[i][p] = params[i..i+3, p]; block 11 = penalties ----
__global__ __launch_bounds__(256) void Decorrelation_prep(
    const float* __restrict__ params,   // [14,496] k-major
    f32x4* __restrict__ ptv,            // [11][496] float4, i-major
    float* __restrict__ pens)           // [3]
{
    const int tid = threadIdx.x;
    const int b   = blockIdx.x;
    if (b < NINT) {
        const int i = b;
        for (int p = tid; p < NPAIR; p += 256) {
            f32x4 w = { params[(i    ) * NPAIR + p],
                        params[(i + 1) * NPAIR + p],
                        params[(i + 2) * NPAIR + p],
                        params[(i + 3) * NPAIR + p] };
            ptv[i * NPAIR + p] = w;
        }
    } else {
        float s2 = 0.f, s1 = 0.f, sp = 0.f;
        for (int idx = tid; idx < NPARAM; idx += 256) {
            const float a = params[idx];
            sp += a * a;
            if (idx < NPARAM - NPAIR) {
                const float bb = params[idx + NPAIR];
                const float d1 = bb - a;
                s1 += d1 * d1;
                if (idx < NPARAM - 2 * NPAIR) {
                    const float cc = params[idx + 2 * NPAIR];
                    const float d2 = cc - 2.f * bb + a;
                    s2 += d2 * d2;
                }
            }
        }
        #pragma unroll
        for (int off = 32; off > 0; off >>= 1) {
            s2 += __shfl_down(s2, off);
            s1 += __shfl_down(s1, off);
            sp += __shfl_down(sp, off);
        }
        __shared__ float ws[3][4];
        const int lane = tid & 63, wid = tid >> 6;
        if (lane == 0) { ws[0][wid] = s2; ws[1][wid] = s1; ws[2][wid] = sp; }
        __syncthreads();
        if (tid == 0) {
            pens[0] = ws[0][0] + ws[0][1] + ws[0][2] + ws[0][3];
            pens[1] = ws[1][0] + ws[1][1] + ws[1][2] + ws[1][3];
            pens[2] = ws[2][0] + ws[2][1] + ws[2][2] + ws[2][3];
        }
    }
}

// ---- Main: 2048 blocks x 256 threads; NO __syncthreads.
// Each wave owns 2 rows end-to-end; LDS strip is wave-private.
__global__ __launch_bounds__(256, 6) void Decorrelation_35270271435435_kernel(
    const float* __restrict__ input,    // [N,32]
    const f32x4* __restrict__ ptv,      // [11][496] tap windows, i-major
    float* __restrict__ out,            // [N,32]
    float* __restrict__ lm,             // [N,32,32]
    int N)
{
    __shared__ float lam[ROWS][LROW];   // 17.4 KB, rows 2w,2w+1 owned by wave w

    const int tid  = threadIdx.x;
    const int wave = tid >> 6;          // 0..3
    const int lane = tid & 63;
    const int n0   = blockIdx.x * ROWS;

    // ---- Per-lane pair decode for the 8 gather slots (hoisted; reused per row) ----
    int  oo[8], cc[8], pp[8];
    bool act[8];
    #pragma unroll
    for (int k = 0; k < 8; ++k) {
        const int p = lane + 64 * k;
        act[k] = (p < NPAIR);
        const int pe = act[k] ? p : (NPAIR - 1);
        int v = (int)((1.0f + sqrtf(8.0f * (float)pe + 1.0f)) * 0.5f);
        while (v * (v - 1) / 2 > pe) --v;
        while ((v + 1) * v / 2 <= pe) ++v;
        const int c = pe - v * (v - 1) / 2;
        pp[k] = pe; cc[k] = c; oo[k] = seg_of(v) + c;
    }

    const float dist  = 30.0f / 11.0f;
    const float invd  = 11.0f / 30.0f;
    const float t0    = -15.0f - 3.0f * dist;
    const float sixth = 1.0f / 6.0f;

    // ---- Phase A (per wave): lam for rows 2w, 2w+1 ----
    #pragma unroll
    for (int rr = 0; rr < 2; ++rr) {
        const int r = wave * 2 + rr;
        const int n = n0 + r;
        if (n >= N) break;
        const float* xrow = input + n * VDIM;
        #pragma unroll
        for (int k = 0; k < 8; ++k) {
            const float xi = xrow[cc[k]];            // L1 broadcast (row = 128 B)
            float x = fminf(fmaxf(xi, -15.0f), 15.0f - 1e-6f);
            float u = (x - t0) * invd;
            int   i = (int)floorf(u);
            i = min(13, max(3, i));
            const float uu  = u - (float)i;
            const float om  = 1.0f - uu;
            const float uu2 = uu * uu, uu3 = uu2 * uu;
            const float w0 = om * om * om * sixth;
            const float w1 = (3.0f * uu3 - 6.0f * uu2 + 4.0f) * sixth;
            const float w2 = (-3.0f * uu3 + 3.0f * uu2 + 3.0f * uu + 1.0f) * sixth;
            const float w3 = uu3 * sixth;
            const f32x4 q  = ptv[(i - 3) * NPAIR + pp[k]];  // lanes contiguous in p
            const float lv = w0 * q.x + w1 * q.y + w2 * q.z + w3 * q.w;
            if (act[k]) lam[r][oo[k]] = lv;
        }
    }

    // ---- Phase B (same wave, no barrier): stream lm + out for rows 2w, 2w+1 ----
    #pragma unroll
    for (int rr = 0; rr < 2; ++rr) {
        const int r = wave * 2 + rr;
        const int n = n0 + r;
        if (n >= N) break;
        const float* xrow  = input + n * VDIM;
        float*       lmrow = lm + (size_t)n * (VDIM * VDIM);
        #pragma unroll
        for (int j = 0; j < 4; ++j) {
            const int v  = j * 8 + (lane >> 3);
            const int c0 = (lane & 7) << 2;
            const f32x4 lq = *(const f32x4*)&lam[r][seg_of(v) + c0];
            const f32x4 xq = *(const f32x4*)(xrow + c0);
            float vals[4];
            float partial = 0.0f;
            #pragma unroll
            for (int t = 0; t < 4; ++t) {
                const int c = c0 + t;
                const float lv = (t == 0) ? lq.x : (t == 1) ? lq.y : (t == 2) ? lq.z : lq.w;
                const float xv = (t == 0) ? xq.x : (t == 1) ? xq.y : (t == 2) ? xq.z : xq.w;
                const float val = (c < v) ? lv : ((c == v) ? 1.0f : 0.0f);
                vals[t] = val;
                partial += val * xv;
            }
            f32x4 f4 = { vals[0], vals[1], vals[2], vals[3] };
            *(f32x4*)(lmrow + j * 256 + lane * 4) = f4;   // plain coalesced store

            partial += __shfl_down(partial, 4, 8);
            partial += __shfl_down(partial, 2, 8);
            partial += __shfl_down(partial, 1, 8);
            if ((lane & 7) == 0) out[n * VDIM + v] = partial;
        }
    }
}

extern "C" void kernel_launch(void* const* d_in, const int* in_sizes, int n_in,
                              void* d_out, int out_size, void* d_ws, size_t ws_size,
                              hipStream_t stream) {
    const float* input  = (const float*)d_in[0];   // [N,32]
    // d_in[1] = log_d : unused by the reference
    const float* params = (const float*)d_in[2];   // [14,496]
    const int N = in_sizes[0] / VDIM;              // 16384

    float* out  = (float*)d_out;                   // [N,32]
    float* lm   = out + (size_t)N * VDIM;          // [N,32,32]
    float* pens = lm + (size_t)N * VDIM * VDIM;    // [3]

    f32x4* ptv = (f32x4*)d_ws;                     // [11][496] float4 = 87 KB

    Decorrelation_prep<<<NINT + 1, 256, 0, stream>>>(params, ptv, pens);

    const int nb = (N + ROWS - 1) / ROWS;          // 2048
    Decorrelation_35270271435435_kernel<<<nb, 256, 0, stream>>>(
        input, ptv, out, lm, N);
}